// Round 13
// baseline (50.607 us; speedup 1.0000x reference)
//
#include <hip/hip_runtime.h>

#define Oo    32
#define F2    4096
#define NTILE 256            // pixel tiles of 16
#define GRID  512            // (oq:2) x (tile:256) -> 2 blocks/CU
#define NBH   4              // batch groups per block (8 batches each)
#define SLOTS (NTILE * NBH)  // per-o partial slots: tile x bh
#define NTOT  (32 * F2)

typedef _Float16 h2 __attribute__((ext_vector_type(2)));
typedef _Float16 h8 __attribute__((ext_vector_type(8)));

#if __has_builtin(__builtin_amdgcn_fdot2)
#define DOT2(a, b, c) __builtin_amdgcn_fdot2((a), (b), (c), false)
#else
__device__ __forceinline__ float DOT2(h2 a, h2 b, float c) {
    return c + (float)a.x * (float)b.x + (float)a.y * (float)b.y;
}
#endif

__device__ __forceinline__ unsigned pkh2f(float a, float b) {
    h2 t; t.x = (_Float16)a; t.y = (_Float16)b;
    return __builtin_bit_cast(unsigned, t);
}
__device__ __forceinline__ h2 bch2(unsigned u) { return __builtin_bit_cast(h2, u); }

// Round-12 economics (2 o's/thread -> og-broadcast pat reads; float4-vectorized
// raw staging) at round-11 occupancy: block = 512 thr (bh:4 x og:8 x f:16),
// grid 512 -> 2 blocks/CU x 8 waves = 16 waves/CU (4/SIMD), vs round 12's
// 2/SIMD (its 1.2us gain showed LDS savings were cancelled by latency
// exposure). Each bh-group: 8 batches = 4 pairs -> 4 barrier-iters/block.
// Per-CU LDS-op / VALU / HBM totals unchanged from round 12. LDS 67.5KB/block
// (2 fit in 160KB). No min-waves launch_bounds (",4" caps VGPR at 64: r7).
template <typename YT>
__global__ __launch_bounds__(512) void svconv_kernel(
    const float* __restrict__ x, const float* __restrict__ wgt,
    const float* __restrict__ bias, YT* __restrict__ y,
    float* __restrict__ psum, float* __restrict__ psumsq)
{
    __shared__ __align__(16) unsigned patU[NBH][2][2][576];  // [bh][buf][bat]
    __shared__ __align__(16) float4   raw4[NBH][2][2][120];  // [bh][buf][bat]

    const int tid  = threadIdx.x;
    const int f    = tid & 15;
    const int og   = (tid >> 4) & 7;
    const int bh   = tid >> 7;                 // 0..3
    const int t127 = tid & 127;
    const int tile = blockIdx.x & (NTILE - 1);
    const int oq   = blockIdx.x >> 8;          // 0..1
    const int o0   = oq * 16 + og;
    const int o1   = o0 + 8;
    const int fb   = tile * 16;
    const int col  = fb + f;
    const int h    = fb >> 6;
    const int w0   = fb & 63;

    // ---- weights for 2 o's, packed f16 (each weight read once chip-wide) ----
    h2 w2[2][36];
    float bz[2];
#pragma unroll
    for (int j = 0; j < 2; ++j) {
        const int o = j ? o1 : o0;
        const float* wp = wgt + (size_t)(o * 72) * F2 + col;
#pragma unroll
        for (int q = 0; q < 36; ++q) {
            float a = wp[(2 * q) * F2];
            float b = wp[(2 * q + 1) * F2];
            h2 t; t.x = (_Float16)a; t.y = (_Float16)b;
            w2[j][q] = t;
        }
        bz[j] = bias[o * F2 + col];
    }

    // ---- raw staging roles: t127 = seg*5 + g; seg=(c,kh) of 24, g=0..4 ----
    const bool staged = (t127 < 120);
    const int  seg = t127 / 5, g = t127 - 5 * (t127 / 5);
    const int  c_  = seg / 3, kh_ = seg - 3 * (seg / 3);
    const int  gh  = h - 1 + kh_;
    const bool ghOK = ((unsigned)gh < 64u);
    const int  vbase = c_ * 4096 + gh * 64 + w0 + 4 * g;   // g<4: 16B-aligned
    int exo[3];                                             // g==4 extras
    {
        int gws[3] = { w0 - 1, w0 + 16, w0 + 17 };
#pragma unroll
        for (int k = 0; k < 3; ++k)
            exo[k] = (ghOK && (unsigned)gws[k] < 64u)
                         ? (c_ * 4096 + gh * 64 + gws[k]) : -1;
    }

    // ---- expansion slots: s = t127 + k*128 over 576 pat pairs ----
    // raw slot for gw: d = gw - w0; d in [0,16) -> d; d==-1 -> 16; d>=16 -> d+1
    int ri0[5], ri1[5];
#pragma unroll
    for (int k = 0; k < 5; ++k) {
        int s = t127 + k * 128;
        if (s < 576) {
            int pix = s / 36, q = s - pix * 36;
            int p0 = 2 * q, p1 = 2 * q + 1;
            int c0 = p0 / 9, r0 = p0 - c0 * 9, kh0 = r0 / 3, kw0 = r0 - kh0 * 3;
            int c1 = p1 / 9, r1 = p1 - c1 * 9, kh1 = r1 / 3, kw1 = r1 - kh1 * 3;
            int d0 = pix + kw0 - 1, d1 = pix + kw1 - 1;
            int ns0 = (d0 < 0) ? 16 : ((d0 < 16) ? d0 : d0 + 1);
            int ns1 = (d1 < 0) ? 16 : ((d1 < 16) ? d1 : d1 + 1);
            ri0[k] = (c0 * 3 + kh0) * 20 + ns0;
            ri1[k] = (c1 * 3 + kh1) * 20 + ns1;
        } else { ri0[k] = 0; ri1[k] = 0; }
    }

    float4 v0, v1;               // one pair in flight
    const int b0 = bh * 8;       // 8 batches per bh-group

    auto ISSUE = [&](int pr) {
        const int ba = b0 + 2 * pr;
        if (staged) {
            if (g < 4) {
                if (ghOK) {
                    v0 = *(const float4*)(x + ba * 32768 + vbase);
                    v1 = *(const float4*)(x + (ba + 1) * 32768 + vbase);
                } else {
                    v0 = make_float4(0.f, 0.f, 0.f, 0.f);
                    v1 = v0;
                }
            } else {
                v0.x = (exo[0] >= 0) ? x[ba * 32768 + exo[0]] : 0.f;
                v0.y = (exo[1] >= 0) ? x[ba * 32768 + exo[1]] : 0.f;
                v0.z = (exo[2] >= 0) ? x[ba * 32768 + exo[2]] : 0.f;
                v0.w = 0.f;
                v1.x = (exo[0] >= 0) ? x[(ba + 1) * 32768 + exo[0]] : 0.f;
                v1.y = (exo[1] >= 0) ? x[(ba + 1) * 32768 + exo[1]] : 0.f;
                v1.z = (exo[2] >= 0) ? x[(ba + 1) * 32768 + exo[2]] : 0.f;
                v1.w = 0.f;
            }
        }
    };
    auto RAWWR = [&](int rbuf) {         // one b128 per batch
        if (staged) {
            raw4[bh][rbuf][0][t127] = v0;
            raw4[bh][rbuf][1][t127] = v1;
        }
    };
    auto EXPAND = [&](int rbuf, int pbuf) {
        const float* rb0 = (const float*)&raw4[bh][rbuf][0][0];
        const float* rb1 = (const float*)&raw4[bh][rbuf][1][0];
#pragma unroll
        for (int k = 0; k < 5; ++k)
            if (k < 4 || t127 < 64) {
                patU[bh][pbuf][0][t127 + k * 128] = pkh2f(rb0[ri0[k]], rb0[ri1[k]]);
                patU[bh][pbuf][1][t127 + k * 128] = pkh2f(rb1[ri0[k]], rb1[ri1[k]]);
            }
    };

    // ---- prologue: pat0=pair0, raw0=pair1, regs=pair2 ----
    ISSUE(0); RAWWR(1);
    __syncthreads();
    EXPAND(1, 0);
    ISSUE(1); RAWWR(0);
    ISSUE(2);
    __syncthreads();

    float s0 = 0.f, ss0 = 0.f, s1 = 0.f, ss1 = 0.f;
#pragma unroll
    for (int t = 0; t < 4; ++t) {
        const int pb = t & 1;

        if (t < 3) EXPAND(t & 1, pb ^ 1);      // pair t+1 -> pat
        if (t < 2) RAWWR((t + 1) & 1);         // pair t+2 -> raw
        if (t < 1) ISSUE(t + 3);               // pair t+3 -> regs

        const uint4* pvA = (const uint4*)&patU[bh][pb][0][f * 36];
        const uint4* pvB = (const uint4*)&patU[bh][pb][1][f * 36];
        float a00 = bz[0], a01 = bz[0], a10 = bz[1], a11 = bz[1];
#pragma unroll
        for (int q = 0; q < 9; ++q) {
            uint4 xA = pvA[q], xB = pvB[q];
            a00 = DOT2(w2[0][4 * q + 0], bch2(xA.x), a00);
            a01 = DOT2(w2[0][4 * q + 0], bch2(xB.x), a01);
            a10 = DOT2(w2[1][4 * q + 0], bch2(xA.x), a10);
            a11 = DOT2(w2[1][4 * q + 0], bch2(xB.x), a11);
            a00 = DOT2(w2[0][4 * q + 1], bch2(xA.y), a00);
            a01 = DOT2(w2[0][4 * q + 1], bch2(xB.y), a01);
            a10 = DOT2(w2[1][4 * q + 1], bch2(xA.y), a10);
            a11 = DOT2(w2[1][4 * q + 1], bch2(xB.y), a11);
            a00 = DOT2(w2[0][4 * q + 2], bch2(xA.z), a00);
            a01 = DOT2(w2[0][4 * q + 2], bch2(xB.z), a01);
            a10 = DOT2(w2[1][4 * q + 2], bch2(xA.z), a10);
            a11 = DOT2(w2[1][4 * q + 2], bch2(xB.z), a11);
            a00 = DOT2(w2[0][4 * q + 3], bch2(xA.w), a00);
            a01 = DOT2(w2[0][4 * q + 3], bch2(xB.w), a01);
            a10 = DOT2(w2[1][4 * q + 3], bch2(xA.w), a10);
            a11 = DOT2(w2[1][4 * q + 3], bch2(xB.w), a11);
        }

        const int ba = b0 + 2 * t;
        y[(size_t)(ba * Oo + o0) * F2 + col]       = (YT)a00;
        y[(size_t)(ba * Oo + o1) * F2 + col]       = (YT)a10;
        y[(size_t)((ba + 1) * Oo + o0) * F2 + col] = (YT)a01;
        y[(size_t)((ba + 1) * Oo + o1) * F2 + col] = (YT)a11;
        s0 += a00 + a01; ss0 = fmaf(a00, a00, ss0); ss0 = fmaf(a01, a01, ss0);
        s1 += a10 + a11; ss1 = fmaf(a10, a10, ss1); ss1 = fmaf(a11, a11, ss1);
        __syncthreads();
    }

    // ---- BN partials ----
    if (psum != nullptr) {
#pragma unroll
        for (int d = 8; d >= 1; d >>= 1) {
            s0  += __shfl_down(s0,  d, 16);
            ss0 += __shfl_down(ss0, d, 16);
            s1  += __shfl_down(s1,  d, 16);
            ss1 += __shfl_down(ss1, d, 16);
        }
        if (f == 0) {
            const int slot = tile * NBH + bh;
            psum[o0 * SLOTS + slot]   = s0;
            psumsq[o0 * SLOTS + slot] = ss0;
            psum[o1 * SLOTS + slot]   = s1;
            psumsq[o1 * SLOTS + slot] = ss1;
        }
    }
}

__global__ __launch_bounds__(256) void bnstats_kernel(
    const float* __restrict__ psum, const float* __restrict__ psumsq,
    const float* __restrict__ gamma, const float* __restrict__ beta,
    float* __restrict__ scsh)
{
    const int o = blockIdx.x;
    const int t = threadIdx.x;
    float s = 0.f, ss = 0.f;
#pragma unroll
    for (int i = 0; i < SLOTS / 256; ++i) {
        s  += psum[o * SLOTS + t + 256 * i];
        ss += psumsq[o * SLOTS + t + 256 * i];
    }
#pragma unroll
    for (int d = 32; d >= 1; d >>= 1) {
        s  += __shfl_down(s, d, 64);
        ss += __shfl_down(ss, d, 64);
    }
    __shared__ float ls[4], lss[4];
    int wv = t >> 6, ln = t & 63;
    if (ln == 0) { ls[wv] = s; lss[wv] = ss; }
    __syncthreads();
    if (t == 0) {
        float S   = (ls[0] + ls[1]) + (ls[2] + ls[3]);
        float SS  = (lss[0] + lss[1]) + (lss[2] + lss[3]);
        float mean = S / (float)NTOT;
        float var  = SS / (float)NTOT - mean * mean;
        float rstd = rsqrtf(var + 1e-5f);
        float scl  = gamma[o] * rstd;
        scsh[o]      = scl;
        scsh[Oo + o] = beta[o] - mean * scl;
    }
}

// ---- primary apply: read f16 y from ws, write fp32 to d_out ----
__global__ __launch_bounds__(256) void bnapply_f16_kernel(
    const _Float16* __restrict__ yh, const float* __restrict__ scsh,
    float* __restrict__ y)
{
    int i = blockIdx.x * 256 + threadIdx.x;    // 8-element packs; 524288 total
    h8 v = ((const h8*)yh)[i];
    int o = (i >> 9) & 31;
    float scl = scsh[o], sh = scsh[Oo + o];
    float4 lo, hi;
    lo.x = fmaf((float)v[0], scl, sh);
    lo.y = fmaf((float)v[1], scl, sh);
    lo.z = fmaf((float)v[2], scl, sh);
    lo.w = fmaf((float)v[3], scl, sh);
    hi.x = fmaf((float)v[4], scl, sh);
    hi.y = fmaf((float)v[5], scl, sh);
    hi.z = fmaf((float)v[6], scl, sh);
    hi.w = fmaf((float)v[7], scl, sh);
    ((float4*)y)[2 * i]     = lo;
    ((float4*)y)[2 * i + 1] = hi;
}

// ---- fallback apply: fp32 in place ----
__global__ __launch_bounds__(256) void bnapply_kernel(
    float* __restrict__ y, const float* __restrict__ scsh)
{
    int i = blockIdx.x * 256 + threadIdx.x;    // float4 index
    float4 v = ((const float4*)y)[i];
    int o = (i >> 10) & 31;
    float scl = scsh[o], sh = scsh[Oo + o];
    v.x = fmaf(v.x, scl, sh);
    v.y = fmaf(v.y, scl, sh);
    v.z = fmaf(v.z, scl, sh);
    v.w = fmaf(v.w, scl, sh);
    ((float4*)y)[i] = v;
}

// ---- tiny-scratch stats fallback: reduce y directly ----
__global__ __launch_bounds__(256) void bnreduce_y_kernel(
    const float* __restrict__ y, float* __restrict__ seg, float* __restrict__ segsq)
{
    const int o  = blockIdx.x >> 3;
    const int sg = blockIdx.x & 7;
    const int t  = threadIdx.x;
    float s = 0.f, ss = 0.f;
    for (int i = t; i < 4 * 1024; i += 256) {
        int b   = sg * 4 + (i >> 10);
        int fof = (i & 1023) * 4;
        float4 v = *(const float4*)(y + (size_t)(b * Oo + o) * F2 + fof);
        s  += (v.x + v.y) + (v.z + v.w);
        ss += v.x * v.x + v.y * v.y + v.z * v.z + v.w * v.w;
    }
#pragma unroll
    for (int d = 32; d >= 1; d >>= 1) {
        s  += __shfl_down(s, d, 64);
        ss += __shfl_down(ss, d, 64);
    }
    __shared__ float ls[4], lss[4];
    int wv = t >> 6, ln = t & 63;
    if (ln == 0) { ls[wv] = s; lss[wv] = ss; }
    __syncthreads();
    if (t == 0) {
        seg[blockIdx.x]   = (ls[0] + ls[1]) + (ls[2] + ls[3]);
        segsq[blockIdx.x] = (lss[0] + lss[1]) + (lss[2] + lss[3]);
    }
}

__global__ __launch_bounds__(256) void bnstats2_kernel(
    const float* __restrict__ seg, const float* __restrict__ segsq,
    const float* __restrict__ gamma, const float* __restrict__ beta,
    float* __restrict__ scsh)
{
    const int t = threadIdx.x;
    const int o = t >> 3, g = t & 7;
    float v  = seg[t];
    float vv = segsq[t];
#pragma unroll
    for (int d = 4; d >= 1; d >>= 1) {
        v  += __shfl_down(v,  d, 8);
        vv += __shfl_down(vv, d, 8);
    }
    if (g == 0) {
        float mean = v / (float)NTOT;
        float var  = vv / (float)NTOT - mean * mean;
        float rstd = rsqrtf(var + 1e-5f);
        float scl  = gamma[o] * rstd;
        scsh[o]      = scl;
        scsh[Oo + o] = beta[o] - mean * scl;
    }
}

extern "C" void kernel_launch(void* const* d_in, const int* in_sizes, int n_in,
                              void* d_out, int out_size, void* d_ws, size_t ws_size,
                              hipStream_t stream)
{
    const float* x     = (const float*)d_in[0];
    const float* wgt   = (const float*)d_in[1];
    const float* bias  = (const float*)d_in[2];
    const float* gamma = (const float*)d_in[3];
    const float* beta  = (const float*)d_in[4];
    float* y = (float*)d_out;

    const size_t n_elems    = (size_t)NTOT * Oo;              // 4,194,304
    const size_t yh_bytes   = n_elems * sizeof(_Float16);     // 8 MiB
    const size_t psum_bytes = (size_t)(2 * Oo * SLOTS + 2 * Oo) * sizeof(float);

    if (ws_size >= yh_bytes + psum_bytes) {
        // primary: f16 intermediate y in ws
        _Float16* yh  = (_Float16*)d_ws;
        float* psum   = (float*)((char*)d_ws + yh_bytes);     // [Oo][SLOTS]
        float* psumsq = psum + Oo * SLOTS;
        float* scsh   = psumsq + Oo * SLOTS;                  // [2][Oo]
        svconv_kernel<_Float16><<<GRID, 512, 0, stream>>>(x, wgt, bias, yh, psum, psumsq);
        bnstats_kernel<<<Oo, 256, 0, stream>>>(psum, psumsq, gamma, beta, scsh);
        bnapply_f16_kernel<<<(int)(n_elems / 8 / 256), 256, 0, stream>>>(yh, scsh, y);
    } else if (ws_size >= psum_bytes) {
        // secondary: fp32 y in d_out, partials in ws
        float* psum   = (float*)d_ws;
        float* psumsq = psum + Oo * SLOTS;
        float* scsh   = psumsq + Oo * SLOTS;
        svconv_kernel<float><<<GRID, 512, 0, stream>>>(x, wgt, bias, y, psum, psumsq);
        bnstats_kernel<<<Oo, 256, 0, stream>>>(psum, psumsq, gamma, beta, scsh);
        bnapply_kernel<<<(int)(n_elems / 4 / 256), 256, 0, stream>>>(y, scsh);
    } else {
        // tertiary: tiny scratch — reduce y directly
        float* seg   = (float*)d_ws;                          // [256]
        float* segsq = seg + 256;
        float* scsh  = segsq + 256;
        svconv_kernel<float><<<GRID, 512, 0, stream>>>(x, wgt, bias, y, nullptr, nullptr);
        bnreduce_y_kernel<<<256, 256, 0, stream>>>(y, seg, segsq);
        bnstats2_kernel<<<1, 256, 0, stream>>>(seg, segsq, gamma, beta, scsh);
        bnapply_kernel<<<(int)(n_elems / 4 / 256), 256, 0, stream>>>(y, scsh);
    }
}

// Round 14
// 44.340 us; speedup vs baseline: 1.1413x; 1.1413x over previous
//
#include <hip/hip_runtime.h>

#define Oo    32
#define F2    4096
#define NTILE 256            // pixel tiles of 16
#define GRID  512            // (oq:2) x (tile:256) -> 2 blocks/CU
#define SLOTS (NTILE * 2)    // per-o partial slots: tile x bh
#define NTOT  (32 * F2)
#define RS    20             // LDS row stride (dwords): 16 batches + 4 pad

typedef _Float16 h2 __attribute__((ext_vector_type(2)));
typedef _Float16 h8 __attribute__((ext_vector_type(8)));

#if __has_builtin(__builtin_amdgcn_fdot2)
#define DOT2(a, b, c) __builtin_amdgcn_fdot2((a), (b), (c), false)
#else
__device__ __forceinline__ float DOT2(h2 a, h2 b, float c) {
    return c + (float)a.x * (float)b.x + (float)a.y * (float)b.y;
}
#endif

__device__ __forceinline__ unsigned pkh2f(float a, float b) {
    h2 t; t.x = (_Float16)a; t.y = (_Float16)b;
    return __builtin_bit_cast(unsigned, t);
}
__device__ __forceinline__ h2 bch2(unsigned u) { return __builtin_bit_cast(h2, u); }

// CHANNEL-PAIR restructure. p is contracted as 4 chunks = channel-pairs
// (2cp, 2cp+1); the f16 pair for LDS word (cp,kh,j) = (x[2cp][gh][gw],
// x[2cp+1][gh][gw]) is kw-INDEPENDENT -> the three kw taps are shifted reads
// of one packed row: the round-10..13 EXPAND stage (30 scalar LDS ops/iter,
// the measured LDS-pipe bound) disappears. Staging converts global float4s
// directly into compute layout [kh][j:18][b:16] (row stride 20 dwords ->
// b128 reads are 2-way-bank = free). Chunks are the OUTER loop with all 32
// outputs/thread register-resident (acc[2][16]) -> the 37.7MB weight stream
// (57% of HBM) is prefetched chunk-ahead INSIDE the loop; round-12's ~8-10us
// serial weight phase is gone. 5 barriers total. Block 256 = (bh:2 x og:8 x
// f:16), grid 512 = (oq:2 x tile:256): weights still read exactly once
// chip-wide. No min-waves launch_bounds (",N" caps VGPR: r5/r7 evidence);
// grid-limited 2 blocks/CU makes VGPR~150 harmless.
template <typename YT>
__global__ __launch_bounds__(256) void svconv_kernel(
    const float* __restrict__ x, const float* __restrict__ wgt,
    const float* __restrict__ bias, YT* __restrict__ y,
    float* __restrict__ psum, float* __restrict__ psumsq)
{
    __shared__ __align__(16) unsigned lds[2 * 2 * 3 * 18 * RS];  // [bh][buf][kh][j][b] 17.3KB

    const int tid  = threadIdx.x;
    const int f    = tid & 15;
    const int og   = (tid >> 4) & 7;
    const int bh   = tid >> 7;
    const int t127 = tid & 127;
    const int tile = blockIdx.x & (NTILE - 1);
    const int oq   = blockIdx.x >> 8;          // 0..1
    const int o0   = oq * 16 + og;
    const int o1   = o0 + 8;
    const int fb   = tile * 16;
    const int col  = fb + f;
    const int h    = fb >> 6;
    const int w0   = fb & 63;

    const float* wp0 = wgt + (size_t)(o0 * 72) * F2 + col;
    const float* wp1 = wgt + (size_t)(o1 * 72) * F2 + col;
    const float bz0 = bias[o0 * F2 + col];
    const float bz1 = bias[o1 * F2 + col];

    // ---- staging slots: 240 per bh-half = (b_:16) x (kh:3) x (s:5) ----
    // s<4: one aligned float4 per channel covering j=1+4s..4+4s (gw=w0+4s..+3)
    // s==4: edge scalars j=0 (gw=w0-1) and j=17 (gw=w0+16)
    int  voff[2], e0[2], e1[2], loff[2];
    bool isEdge[2], valid[2];
#pragma unroll
    for (int m = 0; m < 2; ++m) {
        int sl = t127 + m * 128;
        valid[m] = (sl < 240);
        int b_ = sl / 15, r = sl - 15 * b_;
        if (!valid[m]) { b_ = 0; r = 0; }
        int kh = r / 5, s = r - 5 * kh;
        int gh = h - 1 + kh;
        bool ghOK = ((unsigned)gh < 64u);
        int rowb = (bh * 16 + b_) * 32768 + gh * 64;
        isEdge[m] = (s == 4);
        if (s < 4) {
            voff[m] = ghOK ? (rowb + w0 + 4 * s) : -1;
            e0[m] = -1; e1[m] = -1;
            loff[m] = kh * (18 * RS) + (1 + 4 * s) * RS + b_;
        } else {
            voff[m] = -1;
            e0[m] = (ghOK && w0 > 0)  ? (rowb + w0 - 1)  : -1;
            e1[m] = (ghOK && w0 < 48) ? (rowb + w0 + 16) : -1;
            loff[m] = kh * (18 * RS) + b_;                  // j=0; j=17 at +17*RS
        }
    }

    float acc[2][16];
#pragma unroll
    for (int j = 0; j < 2; ++j)
#pragma unroll
        for (int k = 0; k < 16; ++k) acc[j][k] = 0.f;

    float4 xa[2], xb[2];          // staged x (ch0, ch1) per slot
    float  wpre[2][18];           // prefetched weights for next chunk
    h2     w2[2][9];              // packed weights for current chunk

    auto ISSUEX = [&](int cp) {
        const int co = cp * 8192;                  // ch0 = 2cp*4096
#pragma unroll
        for (int m = 0; m < 2; ++m) {
            xa[m] = make_float4(0.f, 0.f, 0.f, 0.f);
            xb[m] = xa[m];
            if (valid[m]) {
                if (!isEdge[m]) {
                    if (voff[m] >= 0) {
                        xa[m] = *(const float4*)(x + voff[m] + co);
                        xb[m] = *(const float4*)(x + voff[m] + co + 4096);
                    }
                } else {
                    if (e0[m] >= 0) { xa[m].x = x[e0[m] + co]; xb[m].x = x[e0[m] + co + 4096]; }
                    if (e1[m] >= 0) { xa[m].y = x[e1[m] + co]; xb[m].y = x[e1[m] + co + 4096]; }
                }
            }
        }
    };
    auto ISSUEW = [&](int cp) {
#pragma unroll
        for (int k = 0; k < 18; ++k) {
            wpre[0][k] = wp0[(cp * 18 + k) * F2];
            wpre[1][k] = wp1[(cp * 18 + k) * F2];
        }
    };
    auto PACKW = [&]() {          // w2[o][k] = (w[2cp*9+k], w[(2cp+1)*9+k])
#pragma unroll
        for (int j = 0; j < 2; ++j)
#pragma unroll
            for (int k = 0; k < 9; ++k) {
                h2 t; t.x = (_Float16)wpre[j][k]; t.y = (_Float16)wpre[j][9 + k];
                w2[j][k] = t;
            }
    };
    auto WRITEX = [&](int buf) {
        unsigned* base = lds + bh * 2160 + buf * 1080;
#pragma unroll
        for (int m = 0; m < 2; ++m) {
            if (valid[m]) {
                if (!isEdge[m]) {
                    base[loff[m]]          = pkh2f(xa[m].x, xb[m].x);
                    base[loff[m] + RS]     = pkh2f(xa[m].y, xb[m].y);
                    base[loff[m] + 2 * RS] = pkh2f(xa[m].z, xb[m].z);
                    base[loff[m] + 3 * RS] = pkh2f(xa[m].w, xb[m].w);
                } else {
                    base[loff[m]]           = pkh2f(xa[m].x, xb[m].x);
                    base[loff[m] + 17 * RS] = pkh2f(xa[m].y, xb[m].y);
                }
            }
        }
    };
    auto COMPUTE = [&](int buf) {
        const unsigned* base = lds + bh * 2160 + buf * 1080;
#pragma unroll
        for (int kh = 0; kh < 3; ++kh) {
#pragma unroll
            for (int kw = 0; kw < 3; ++kw) {
                const int k = kh * 3 + kw;
                const uint4* row = (const uint4*)(base + kh * (18 * RS) + (f + kw) * RS);
#pragma unroll
                for (int q4 = 0; q4 < 4; ++q4) {
                    uint4 u = row[q4];
                    acc[0][4 * q4 + 0] = DOT2(w2[0][k], bch2(u.x), acc[0][4 * q4 + 0]);
                    acc[0][4 * q4 + 1] = DOT2(w2[0][k], bch2(u.y), acc[0][4 * q4 + 1]);
                    acc[0][4 * q4 + 2] = DOT2(w2[0][k], bch2(u.z), acc[0][4 * q4 + 2]);
                    acc[0][4 * q4 + 3] = DOT2(w2[0][k], bch2(u.w), acc[0][4 * q4 + 3]);
                    acc[1][4 * q4 + 0] = DOT2(w2[1][k], bch2(u.x), acc[1][4 * q4 + 0]);
                    acc[1][4 * q4 + 1] = DOT2(w2[1][k], bch2(u.y), acc[1][4 * q4 + 1]);
                    acc[1][4 * q4 + 2] = DOT2(w2[1][k], bch2(u.z), acc[1][4 * q4 + 2]);
                    acc[1][4 * q4 + 3] = DOT2(w2[1][k], bch2(u.w), acc[1][4 * q4 + 3]);
                }
            }
        }
    };

    // ---- prologue: chunk0 -> buf0; chunk1 loads in flight ----
    ISSUEX(0); ISSUEW(0);
    WRITEX(0); PACKW();           // w2 = chunk0
    ISSUEX(1); ISSUEW(1);
    __syncthreads();

#pragma unroll
    for (int cp = 0; cp < 4; ++cp) {
        COMPUTE(cp & 1);
        if (cp < 3) {
            WRITEX((cp + 1) & 1);     // chunk cp+1 (regs staged) -> other buffer
            PACKW();                  // w2 = chunk cp+1
            if (cp < 2) { ISSUEX(cp + 2); ISSUEW(cp + 2); }
        }
        __syncthreads();
    }

    // ---- epilogue: bias, y store, BN partials ----
    float s0 = 0.f, ss0 = 0.f, s1 = 0.f, ss1 = 0.f;
#pragma unroll
    for (int bi = 0; bi < 16; ++bi) {
        const int b = bh * 16 + bi;
        float a0 = acc[0][bi] + bz0;
        float a1 = acc[1][bi] + bz1;
        y[(size_t)(b * Oo + o0) * F2 + col] = (YT)a0;
        y[(size_t)(b * Oo + o1) * F2 + col] = (YT)a1;
        s0 += a0; ss0 = fmaf(a0, a0, ss0);
        s1 += a1; ss1 = fmaf(a1, a1, ss1);
    }
    if (psum != nullptr) {
#pragma unroll
        for (int d = 8; d >= 1; d >>= 1) {
            s0  += __shfl_down(s0,  d, 16);
            ss0 += __shfl_down(ss0, d, 16);
            s1  += __shfl_down(s1,  d, 16);
            ss1 += __shfl_down(ss1, d, 16);
        }
        if (f == 0) {
            const int slot = tile * 2 + bh;
            psum[o0 * SLOTS + slot]   = s0;
            psumsq[o0 * SLOTS + slot] = ss0;
            psum[o1 * SLOTS + slot]   = s1;
            psumsq[o1 * SLOTS + slot] = ss1;
        }
    }
}

__global__ __launch_bounds__(256) void bnstats_kernel(
    const float* __restrict__ psum, const float* __restrict__ psumsq,
    const float* __restrict__ gamma, const float* __restrict__ beta,
    float* __restrict__ scsh)
{
    const int o = blockIdx.x;
    const int t = threadIdx.x;
    float s  = psum[o * SLOTS + t]   + psum[o * SLOTS + t + 256];
    float ss = psumsq[o * SLOTS + t] + psumsq[o * SLOTS + t + 256];
#pragma unroll
    for (int d = 32; d >= 1; d >>= 1) {
        s  += __shfl_down(s, d, 64);
        ss += __shfl_down(ss, d, 64);
    }
    __shared__ float ls[4], lss[4];
    int wv = t >> 6, ln = t & 63;
    if (ln == 0) { ls[wv] = s; lss[wv] = ss; }
    __syncthreads();
    if (t == 0) {
        float S   = (ls[0] + ls[1]) + (ls[2] + ls[3]);
        float SS  = (lss[0] + lss[1]) + (lss[2] + lss[3]);
        float mean = S / (float)NTOT;
        float var  = SS / (float)NTOT - mean * mean;
        float rstd = rsqrtf(var + 1e-5f);
        float scl  = gamma[o] * rstd;
        scsh[o]      = scl;
        scsh[Oo + o] = beta[o] - mean * scl;
    }
}

// ---- primary apply: read f16 y from ws, write fp32 to d_out ----
__global__ __launch_bounds__(256) void bnapply_f16_kernel(
    const _Float16* __restrict__ yh, const float* __restrict__ scsh,
    float* __restrict__ y)
{
    int i = blockIdx.x * 256 + threadIdx.x;    // 8-element packs; 524288 total
    h8 v = ((const h8*)yh)[i];
    int o = (i >> 9) & 31;
    float scl = scsh[o], sh = scsh[Oo + o];
    float4 lo, hi;
    lo.x = fmaf((float)v[0], scl, sh);
    lo.y = fmaf((float)v[1], scl, sh);
    lo.z = fmaf((float)v[2], scl, sh);
    lo.w = fmaf((float)v[3], scl, sh);
    hi.x = fmaf((float)v[4], scl, sh);
    hi.y = fmaf((float)v[5], scl, sh);
    hi.z = fmaf((float)v[6], scl, sh);
    hi.w = fmaf((float)v[7], scl, sh);
    ((float4*)y)[2 * i]     = lo;
    ((float4*)y)[2 * i + 1] = hi;
}

// ---- fallback apply: fp32 in place ----
__global__ __launch_bounds__(256) void bnapply_kernel(
    float* __restrict__ y, const float* __restrict__ scsh)
{
    int i = blockIdx.x * 256 + threadIdx.x;    // float4 index
    float4 v = ((const float4*)y)[i];
    int o = (i >> 10) & 31;
    float scl = scsh[o], sh = scsh[Oo + o];
    v.x = fmaf(v.x, scl, sh);
    v.y = fmaf(v.y, scl, sh);
    v.z = fmaf(v.z, scl, sh);
    v.w = fmaf(v.w, scl, sh);
    ((float4*)y)[i] = v;
}

// ---- tiny-scratch stats fallback: reduce y directly ----
__global__ __launch_bounds__(256) void bnreduce_y_kernel(
    const float* __restrict__ y, float* __restrict__ seg, float* __restrict__ segsq)
{
    const int o  = blockIdx.x >> 3;
    const int sg = blockIdx.x & 7;
    const int t  = threadIdx.x;
    float s = 0.f, ss = 0.f;
    for (int i = t; i < 4 * 1024; i += 256) {
        int b   = sg * 4 + (i >> 10);
        int fof = (i & 1023) * 4;
        float4 v = *(const float4*)(y + (size_t)(b * Oo + o) * F2 + fof);
        s  += (v.x + v.y) + (v.z + v.w);
        ss += v.x * v.x + v.y * v.y + v.z * v.z + v.w * v.w;
    }
#pragma unroll
    for (int d = 32; d >= 1; d >>= 1) {
        s  += __shfl_down(s, d, 64);
        ss += __shfl_down(ss, d, 64);
    }
    __shared__ float ls[4], lss[4];
    int wv = t >> 6, ln = t & 63;
    if (ln == 0) { ls[wv] = s; lss[wv] = ss; }
    __syncthreads();
    if (t == 0) {
        seg[blockIdx.x]   = (ls[0] + ls[1]) + (ls[2] + ls[3]);
        segsq[blockIdx.x] = (lss[0] + lss[1]) + (lss[2] + lss[3]);
    }
}

__global__ __launch_bounds__(256) void bnstats2_kernel(
    const float* __restrict__ seg, const float* __restrict__ segsq,
    const float* __restrict__ gamma, const float* __restrict__ beta,
    float* __restrict__ scsh)
{
    const int t = threadIdx.x;
    const int o = t >> 3, g = t & 7;
    float v  = seg[t];
    float vv = segsq[t];
#pragma unroll
    for (int d = 4; d >= 1; d >>= 1) {
        v  += __shfl_down(v,  d, 8);
        vv += __shfl_down(vv, d, 8);
    }
    if (g == 0) {
        float mean = v / (float)NTOT;
        float var  = vv / (float)NTOT - mean * mean;
        float rstd = rsqrtf(var + 1e-5f);
        float scl  = gamma[o] * rstd;
        scsh[o]      = scl;
        scsh[Oo + o] = beta[o] - mean * scl;
    }
}

extern "C" void kernel_launch(void* const* d_in, const int* in_sizes, int n_in,
                              void* d_out, int out_size, void* d_ws, size_t ws_size,
                              hipStream_t stream)
{
    const float* x     = (const float*)d_in[0];
    const float* wgt   = (const float*)d_in[1];
    const float* bias  = (const float*)d_in[2];
    const float* gamma = (const float*)d_in[3];
    const float* beta  = (const float*)d_in[4];
    float* y = (float*)d_out;

    const size_t n_elems    = (size_t)NTOT * Oo;              // 4,194,304
    const size_t yh_bytes   = n_elems * sizeof(_Float16);     // 8 MiB
    const size_t psum_bytes = (size_t)(2 * Oo * SLOTS + 2 * Oo) * sizeof(float);

    if (ws_size >= yh_bytes + psum_bytes) {
        // primary: f16 intermediate y in ws
        _Float16* yh  = (_Float16*)d_ws;
        float* psum   = (float*)((char*)d_ws + yh_bytes);     // [Oo][SLOTS]
        float* psumsq = psum + Oo * SLOTS;
        float* scsh   = psumsq + Oo * SLOTS;                  // [2][Oo]
        svconv_kernel<_Float16><<<GRID, 256, 0, stream>>>(x, wgt, bias, yh, psum, psumsq);
        bnstats_kernel<<<Oo, 256, 0, stream>>>(psum, psumsq, gamma, beta, scsh);
        bnapply_f16_kernel<<<(int)(n_elems / 8 / 256), 256, 0, stream>>>(yh, scsh, y);
    } else if (ws_size >= psum_bytes) {
        // secondary: fp32 y in d_out, partials in ws
        float* psum   = (float*)d_ws;
        float* psumsq = psum + Oo * SLOTS;
        float* scsh   = psumsq + Oo * SLOTS;
        svconv_kernel<float><<<GRID, 256, 0, stream>>>(x, wgt, bias, y, psum, psumsq);
        bnstats_kernel<<<Oo, 256, 0, stream>>>(psum, psumsq, gamma, beta, scsh);
        bnapply_kernel<<<(int)(n_elems / 4 / 256), 256, 0, stream>>>(y, scsh);
    } else {
        // tertiary: tiny scratch — reduce y directly
        float* seg   = (float*)d_ws;                          // [256]
        float* segsq = seg + 256;
        float* scsh  = segsq + 256;
        svconv_kernel<float><<<GRID, 256, 0, stream>>>(x, wgt, bias, y, nullptr, nullptr);
        bnreduce_y_kernel<<<256, 256, 0, stream>>>(y, seg, segsq);
        bnstats2_kernel<<<1, 256, 0, stream>>>(seg, segsq, gamma, beta, scsh);
        bnapply_kernel<<<(int)(n_elems / 4 / 256), 256, 0, stream>>>(y, scsh);
    }
}

// Round 15
// 42.857 us; speedup vs baseline: 1.1808x; 1.0346x over previous
//
#include <hip/hip_runtime.h>

#define Oo    32
#define F2    4096
#define NTILE 256            // pixel tiles of 16
#define GRID  512            // (oq:2) x (tile:256) -> 2 blocks/CU
#define SLOTS (NTILE * 2)    // per-o partial slots: tile x bh
#define NTOT  (32 * F2)
#define RS    20             // x-LDS row stride (dwords): 16 batches + 4 pad

typedef _Float16 h2 __attribute__((ext_vector_type(2)));
typedef _Float16 h8 __attribute__((ext_vector_type(8)));

#if __has_builtin(__builtin_amdgcn_fdot2)
#define DOT2(a, b, c) __builtin_amdgcn_fdot2((a), (b), (c), false)
#else
__device__ __forceinline__ float DOT2(h2 a, h2 b, float c) {
    return c + (float)a.x * (float)b.x + (float)a.y * (float)b.y;
}
#endif

__device__ __forceinline__ unsigned pkh2f(float a, float b) {
    h2 t; t.x = (_Float16)a; t.y = (_Float16)b;
    return __builtin_bit_cast(unsigned, t);
}
__device__ __forceinline__ h2 bch2(unsigned u) { return __builtin_bit_cast(h2, u); }

// r14 structure + VECTORIZED WEIGHT STREAM. Diagnosis: all rounds since r9
// sustain only ~1.7TB/s because weights (57% of traffic) are scalar 4B loads
// with ~1.2KB/CU in flight vs the ~9KB needed to cover ~900cy HBM latency.
// Fix: weight slot threads load float4 pairs (w[o][p][c..c+3], w[o][p+9][..])
// -> pack (w[p],w[p+9]) f16 dwords -> one ds_write_b128 into [k:9][o:16][c:16]
// (compute b32 read at k*256+o*16+f: lanes (og:4 x f:16) hit 64 distinct
// dwords = 2-way banks = free). In flight/CU: 512thr x 4.5 f4 x 16B = 36KB.
// x path (ISSUEX/WRITEX/COMPUTE-x, layout, edges) verbatim from r14 (passed).
// 5 barriers; LDS 35.7KB/block; no min-waves launch_bounds (",N" VGPR trap).
template <typename YT>
__global__ __launch_bounds__(256) void svconv_kernel(
    const float* __restrict__ x, const float* __restrict__ wgt,
    const float* __restrict__ bias, YT* __restrict__ y,
    float* __restrict__ psum, float* __restrict__ psumsq)
{
    __shared__ __align__(16) unsigned ldsX[2][2][1080];   // [bh][buf][kh][j][b]
    __shared__ __align__(16) unsigned ldsW[2][2304];      // [buf][k:9][o:16][c:16]

    const int tid  = threadIdx.x;
    const int f    = tid & 15;
    const int og   = (tid >> 4) & 7;
    const int bh   = tid >> 7;
    const int t127 = tid & 127;
    const int tile = blockIdx.x & (NTILE - 1);
    const int oq   = blockIdx.x >> 8;          // 0..1
    const int o0   = oq * 16 + og;
    const int o1   = o0 + 8;
    const int fb   = tile * 16;
    const int col  = fb + f;
    const int h    = fb >> 6;
    const int w0   = fb & 63;

    const float bz0 = bias[o0 * F2 + col];
    const float bz1 = bias[o1 * F2 + col];

    // ---- weight slots: s = tid + m*256 over 576 = (o:16)x(k:9)x(c4:4) ----
    int  wgo[3], wld[3];
    bool wv[3];
#pragma unroll
    for (int m = 0; m < 3; ++m) {
        int s = tid + m * 256;
        wv[m] = (s < 576);
        int o_ = s / 36, rm = s - 36 * o_;
        if (!wv[m]) { o_ = 0; rm = 0; }
        int k_ = rm >> 2, c4 = rm & 3;
        wgo[m] = ((oq * 16 + o_) * 72 + k_) * F2 + fb + 4 * c4;  // +cp*18*F2 at use
        wld[m] = k_ * 256 + o_ * 16 + c4 * 4;
    }

    // ---- x staging slots: sl = t127 + m*128 over 240 = (b:16)x(kh:3)x(s:5) ----
    int  voff[2], e0[2], e1[2], loff[2];
    bool isEdge[2], valid[2];
#pragma unroll
    for (int m = 0; m < 2; ++m) {
        int sl = t127 + m * 128;
        valid[m] = (sl < 240);
        int b_ = sl / 15, r = sl - 15 * b_;
        if (!valid[m]) { b_ = 0; r = 0; }
        int kh = r / 5, s = r - 5 * kh;
        int gh = h - 1 + kh;
        bool ghOK = ((unsigned)gh < 64u);
        int rowb = (bh * 16 + b_) * 32768 + gh * 64;
        isEdge[m] = (s == 4);
        if (s < 4) {
            voff[m] = ghOK ? (rowb + w0 + 4 * s) : -1;
            e0[m] = -1; e1[m] = -1;
            loff[m] = kh * (18 * RS) + (1 + 4 * s) * RS + b_;
        } else {
            voff[m] = -1;
            e0[m] = (ghOK && w0 > 0)  ? (rowb + w0 - 1)  : -1;
            e1[m] = (ghOK && w0 < 48) ? (rowb + w0 + 16) : -1;
            loff[m] = kh * (18 * RS) + b_;               // j=0; j=17 at +17*RS
        }
    }

    float acc[2][16];
#pragma unroll
    for (int j = 0; j < 2; ++j)
#pragma unroll
        for (int k = 0; k < 16; ++k) acc[j][k] = 0.f;

    float4 xa[2], xb[2];          // staged x (ch0, ch1) per slot
    float4 wA[3], wB[3];          // staged weights (p, p+9) per slot

    auto ISSUEX = [&](int cp) {
        const int co = cp * 8192;                  // ch0 = 2cp*4096
#pragma unroll
        for (int m = 0; m < 2; ++m) {
            xa[m] = make_float4(0.f, 0.f, 0.f, 0.f);
            xb[m] = xa[m];
            if (valid[m]) {
                if (!isEdge[m]) {
                    if (voff[m] >= 0) {
                        xa[m] = *(const float4*)(x + voff[m] + co);
                        xb[m] = *(const float4*)(x + voff[m] + co + 4096);
                    }
                } else {
                    if (e0[m] >= 0) { xa[m].x = x[e0[m] + co]; xb[m].x = x[e0[m] + co + 4096]; }
                    if (e1[m] >= 0) { xa[m].y = x[e1[m] + co]; xb[m].y = x[e1[m] + co + 4096]; }
                }
            }
        }
    };
    auto ISSUEW = [&](int cp) {
        const int off = cp * 18 * F2;
#pragma unroll
        for (int m = 0; m < 3; ++m)
            if (wv[m]) {
                wA[m] = *(const float4*)(wgt + wgo[m] + off);
                wB[m] = *(const float4*)(wgt + wgo[m] + off + 9 * F2);
            }
    };
    auto WRITEX = [&](int buf) {
        unsigned* base = &ldsX[bh][buf][0];
#pragma unroll
        for (int m = 0; m < 2; ++m) {
            if (valid[m]) {
                if (!isEdge[m]) {
                    base[loff[m]]          = pkh2f(xa[m].x, xb[m].x);
                    base[loff[m] + RS]     = pkh2f(xa[m].y, xb[m].y);
                    base[loff[m] + 2 * RS] = pkh2f(xa[m].z, xb[m].z);
                    base[loff[m] + 3 * RS] = pkh2f(xa[m].w, xb[m].w);
                } else {
                    base[loff[m]]           = pkh2f(xa[m].x, xb[m].x);
                    base[loff[m] + 17 * RS] = pkh2f(xa[m].y, xb[m].y);
                }
            }
        }
    };
    auto WRITEW = [&](int buf) {
#pragma unroll
        for (int m = 0; m < 3; ++m)
            if (wv[m]) {
                uint4 pk;
                pk.x = pkh2f(wA[m].x, wB[m].x);
                pk.y = pkh2f(wA[m].y, wB[m].y);
                pk.z = pkh2f(wA[m].z, wB[m].z);
                pk.w = pkh2f(wA[m].w, wB[m].w);
                *(uint4*)&ldsW[buf][wld[m]] = pk;
            }
    };
    auto COMPUTE = [&](int buf) {
        const unsigned* wb = &ldsW[buf][0];
        h2 w2[2][9];
#pragma unroll
        for (int k = 0; k < 9; ++k) {
            w2[0][k] = bch2(wb[k * 256 + og * 16 + f]);
            w2[1][k] = bch2(wb[k * 256 + (og + 8) * 16 + f]);
        }
        const unsigned* base = &ldsX[bh][buf][0];
#pragma unroll
        for (int kh = 0; kh < 3; ++kh) {
#pragma unroll
            for (int kw = 0; kw < 3; ++kw) {
                const int k = kh * 3 + kw;
                const uint4* row = (const uint4*)(base + kh * (18 * RS) + (f + kw) * RS);
#pragma unroll
                for (int q4 = 0; q4 < 4; ++q4) {
                    uint4 u = row[q4];
                    acc[0][4 * q4 + 0] = DOT2(w2[0][k], bch2(u.x), acc[0][4 * q4 + 0]);
                    acc[0][4 * q4 + 1] = DOT2(w2[0][k], bch2(u.y), acc[0][4 * q4 + 1]);
                    acc[0][4 * q4 + 2] = DOT2(w2[0][k], bch2(u.z), acc[0][4 * q4 + 2]);
                    acc[0][4 * q4 + 3] = DOT2(w2[0][k], bch2(u.w), acc[0][4 * q4 + 3]);
                    acc[1][4 * q4 + 0] = DOT2(w2[1][k], bch2(u.x), acc[1][4 * q4 + 0]);
                    acc[1][4 * q4 + 1] = DOT2(w2[1][k], bch2(u.y), acc[1][4 * q4 + 1]);
                    acc[1][4 * q4 + 2] = DOT2(w2[1][k], bch2(u.z), acc[1][4 * q4 + 2]);
                    acc[1][4 * q4 + 3] = DOT2(w2[1][k], bch2(u.w), acc[1][4 * q4 + 3]);
                }
            }
        }
    };

    // ---- prologue: chunk0 -> buf0; chunk1 loads in flight ----
    ISSUEX(0); ISSUEW(0);
    WRITEX(0); WRITEW(0);
    ISSUEX(1); ISSUEW(1);
    __syncthreads();

#pragma unroll
    for (int cp = 0; cp < 4; ++cp) {
        COMPUTE(cp & 1);
        if (cp < 3) {
            WRITEX((cp + 1) & 1);
            WRITEW((cp + 1) & 1);
            if (cp < 2) { ISSUEX(cp + 2); ISSUEW(cp + 2); }
        }
        __syncthreads();
    }

    // ---- epilogue: bias, y store, BN partials ----
    float s0 = 0.f, ss0 = 0.f, s1 = 0.f, ss1 = 0.f;
#pragma unroll
    for (int bi = 0; bi < 16; ++bi) {
        const int b = bh * 16 + bi;
        float a0 = acc[0][bi] + bz0;
        float a1 = acc[1][bi] + bz1;
        y[(size_t)(b * Oo + o0) * F2 + col] = (YT)a0;
        y[(size_t)(b * Oo + o1) * F2 + col] = (YT)a1;
        s0 += a0; ss0 = fmaf(a0, a0, ss0);
        s1 += a1; ss1 = fmaf(a1, a1, ss1);
    }
    if (psum != nullptr) {
#pragma unroll
        for (int d = 8; d >= 1; d >>= 1) {
            s0  += __shfl_down(s0,  d, 16);
            ss0 += __shfl_down(ss0, d, 16);
            s1  += __shfl_down(s1,  d, 16);
            ss1 += __shfl_down(ss1, d, 16);
        }
        if (f == 0) {
            const int slot = tile * 2 + bh;
            psum[o0 * SLOTS + slot]   = s0;
            psumsq[o0 * SLOTS + slot] = ss0;
            psum[o1 * SLOTS + slot]   = s1;
            psumsq[o1 * SLOTS + slot] = ss1;
        }
    }
}

__global__ __launch_bounds__(256) void bnstats_kernel(
    const float* __restrict__ psum, const float* __restrict__ psumsq,
    const float* __restrict__ gamma, const float* __restrict__ beta,
    float* __restrict__ scsh)
{
    const int o = blockIdx.x;
    const int t = threadIdx.x;
    float s  = psum[o * SLOTS + t]   + psum[o * SLOTS + t + 256];
    float ss = psumsq[o * SLOTS + t] + psumsq[o * SLOTS + t + 256];
#pragma unroll
    for (int d = 32; d >= 1; d >>= 1) {
        s  += __shfl_down(s, d, 64);
        ss += __shfl_down(ss, d, 64);
    }
    __shared__ float ls[4], lss[4];
    int wv = t >> 6, ln = t & 63;
    if (ln == 0) { ls[wv] = s; lss[wv] = ss; }
    __syncthreads();
    if (t == 0) {
        float S   = (ls[0] + ls[1]) + (ls[2] + ls[3]);
        float SS  = (lss[0] + lss[1]) + (lss[2] + lss[3]);
        float mean = S / (float)NTOT;
        float var  = SS / (float)NTOT - mean * mean;
        float rstd = rsqrtf(var + 1e-5f);
        float scl  = gamma[o] * rstd;
        scsh[o]      = scl;
        scsh[Oo + o] = beta[o] - mean * scl;
    }
}

// ---- primary apply: read f16 y from ws, write fp32 to d_out ----
__global__ __launch_bounds__(256) void bnapply_f16_kernel(
    const _Float16* __restrict__ yh, const float* __restrict__ scsh,
    float* __restrict__ y)
{
    int i = blockIdx.x * 256 + threadIdx.x;    // 8-element packs; 524288 total
    h8 v = ((const h8*)yh)[i];
    int o = (i >> 9) & 31;
    float scl = scsh[o], sh = scsh[Oo + o];
    float4 lo, hi;
    lo.x = fmaf((float)v[0], scl, sh);
    lo.y = fmaf((float)v[1], scl, sh);
    lo.z = fmaf((float)v[2], scl, sh);
    lo.w = fmaf((float)v[3], scl, sh);
    hi.x = fmaf((float)v[4], scl, sh);
    hi.y = fmaf((float)v[5], scl, sh);
    hi.z = fmaf((float)v[6], scl, sh);
    hi.w = fmaf((float)v[7], scl, sh);
    ((float4*)y)[2 * i]     = lo;
    ((float4*)y)[2 * i + 1] = hi;
}

// ---- fallback apply: fp32 in place ----
__global__ __launch_bounds__(256) void bnapply_kernel(
    float* __restrict__ y, const float* __restrict__ scsh)
{
    int i = blockIdx.x * 256 + threadIdx.x;    // float4 index
    float4 v = ((const float4*)y)[i];
    int o = (i >> 10) & 31;
    float scl = scsh[o], sh = scsh[Oo + o];
    v.x = fmaf(v.x, scl, sh);
    v.y = fmaf(v.y, scl, sh);
    v.z = fmaf(v.z, scl, sh);
    v.w = fmaf(v.w, scl, sh);
    ((float4*)y)[i] = v;
}

// ---- tiny-scratch stats fallback: reduce y directly ----
__global__ __launch_bounds__(256) void bnreduce_y_kernel(
    const float* __restrict__ y, float* __restrict__ seg, float* __restrict__ segsq)
{
    const int o  = blockIdx.x >> 3;
    const int sg = blockIdx.x & 7;
    const int t  = threadIdx.x;
    float s = 0.f, ss = 0.f;
    for (int i = t; i < 4 * 1024; i += 256) {
        int b   = sg * 4 + (i >> 10);
        int fof = (i & 1023) * 4;
        float4 v = *(const float4*)(y + (size_t)(b * Oo + o) * F2 + fof);
        s  += (v.x + v.y) + (v.z + v.w);
        ss += v.x * v.x + v.y * v.y + v.z * v.z + v.w * v.w;
    }
#pragma unroll
    for (int d = 32; d >= 1; d >>= 1) {
        s  += __shfl_down(s, d, 64);
        ss += __shfl_down(ss, d, 64);
    }
    __shared__ float ls[4], lss[4];
    int wv = t >> 6, ln = t & 63;
    if (ln == 0) { ls[wv] = s; lss[wv] = ss; }
    __syncthreads();
    if (t == 0) {
        seg[blockIdx.x]   = (ls[0] + ls[1]) + (ls[2] + ls[3]);
        segsq[blockIdx.x] = (lss[0] + lss[1]) + (lss[2] + lss[3]);
    }
}

__global__ __launch_bounds__(256) void bnstats2_kernel(
    const float* __restrict__ seg, const float* __restrict__ segsq,
    const float* __restrict__ gamma, const float* __restrict__ beta,
    float* __restrict__ scsh)
{
    const int t = threadIdx.x;
    const int o = t >> 3, g = t & 7;
    float v  = seg[t];
    float vv = segsq[t];
#pragma unroll
    for (int d = 4; d >= 1; d >>= 1) {
        v  += __shfl_down(v,  d, 8);
        vv += __shfl_down(vv, d, 8);
    }
    if (g == 0) {
        float mean = v / (float)NTOT;
        float var  = vv / (float)NTOT - mean * mean;
        float rstd = rsqrtf(var + 1e-5f);
        float scl  = gamma[o] * rstd;
        scsh[o]      = scl;
        scsh[Oo + o] = beta[o] - mean * scl;
    }
}

extern "C" void kernel_launch(void* const* d_in, const int* in_sizes, int n_in,
                              void* d_out, int out_size, void* d_ws, size_t ws_size,
                              hipStream_t stream)
{
    const float* x     = (const float*)d_in[0];
    const float* wgt   = (const float*)d_in[1];
    const float* bias  = (const float*)d_in[2];
    const float* gamma = (const float*)d_in[3];
    const float* beta  = (const float*)d_in[4];
    float* y = (float*)d_out;

    const size_t n_elems    = (size_t)NTOT * Oo;              // 4,194,304
    const size_t yh_bytes   = n_elems * sizeof(_Float16);     // 8 MiB
    const size_t psum_bytes = (size_t)(2 * Oo * SLOTS + 2 * Oo) * sizeof(float);

    if (ws_size >= yh_bytes + psum_bytes) {
        // primary: f16 intermediate y in ws
        _Float16* yh  = (_Float16*)d_ws;
        float* psum   = (float*)((char*)d_ws + yh_bytes);     // [Oo][SLOTS]
        float* psumsq = psum + Oo * SLOTS;
        float* scsh   = psumsq + Oo * SLOTS;                  // [2][Oo]
        svconv_kernel<_Float16><<<GRID, 256, 0, stream>>>(x, wgt, bias, yh, psum, psumsq);
        bnstats_kernel<<<Oo, 256, 0, stream>>>(psum, psumsq, gamma, beta, scsh);
        bnapply_f16_kernel<<<(int)(n_elems / 8 / 256), 256, 0, stream>>>(yh, scsh, y);
    } else if (ws_size >= psum_bytes) {
        // secondary: fp32 y in d_out, partials in ws
        float* psum   = (float*)d_ws;
        float* psumsq = psum + Oo * SLOTS;
        float* scsh   = psumsq + Oo * SLOTS;
        svconv_kernel<float><<<GRID, 256, 0, stream>>>(x, wgt, bias, y, psum, psumsq);
        bnstats_kernel<<<Oo, 256, 0, stream>>>(psum, psumsq, gamma, beta, scsh);
        bnapply_kernel<<<(int)(n_elems / 4 / 256), 256, 0, stream>>>(y, scsh);
    } else {
        // tertiary: tiny scratch — reduce y directly
        float* seg   = (float*)d_ws;                          // [256]
        float* segsq = seg + 256;
        float* scsh  = segsq + 256;
        svconv_kernel<float><<<GRID, 256, 0, stream>>>(x, wgt, bias, y, nullptr, nullptr);
        bnreduce_y_kernel<<<256, 256, 0, stream>>>(y, seg, segsq);
        bnstats2_kernel<<<1, 256, 0, stream>>>(seg, segsq, gamma, beta, scsh);
        bnapply_kernel<<<(int)(n_elems / 4 / 256), 256, 0, stream>>>(y, scsh);
    }
}

// Round 16
// 32.064 us; speedup vs baseline: 1.5783x; 1.3366x over previous
//
#include <hip/hip_runtime.h>

#define Oo    32
#define F2    4096
#define GRID  256            // (oq:4) x (h:64) -> 1 block/CU
#define SLOTS 64             // per-o partial slots: one per h-row block
#define NTOT  (32 * F2)

typedef _Float16 h2 __attribute__((ext_vector_type(2)));
typedef _Float16 h8 __attribute__((ext_vector_type(8)));

#if __has_builtin(__builtin_amdgcn_fdot2)
#define DOT2(a, b, c) __builtin_amdgcn_fdot2((a), (b), (c), false)
#else
__device__ __forceinline__ float DOT2(h2 a, h2 b, float c) {
    return c + (float)a.x * (float)b.x + (float)a.y * (float)b.y;
}
#endif

__device__ __forceinline__ unsigned pkh2f(float a, float b) {
    h2 t; t.x = (_Float16)a; t.y = (_Float16)b;
    return __builtin_bit_cast(unsigned, t);
}
__device__ __forceinline__ h2 bch2(unsigned u) { return __builtin_bit_cast(h2, u); }

// FULL-ROW TILE (64 cols). Diagnosis: r10-r15 all sustain ~1.7TB/s because a
// 16-col tile fragments the weight stream into 64B lines at 16KB stride (zero
// DRAM row locality) regardless of how loads are issued; the harness fill
// kernel hits 6.7TB/s on sequential streams. Block = (oq:4 of 8 o's) x (one
// image row h) x (all 32 batches): weight reads become 256B contiguous runs,
// read EXACTLY ONCE chip-wide; x reads are 256B rows; no w-halo (row edges =
// image edges = zeros); gh-halo rows are chunk-invariant (pre-zeroed once).
// Channel-pair chunks (4 x 18p) as r14/15 (proven numerics). x single-buffered
// [kh][b:32][w':68] (per-chunk geometry identical, only channels change; two
// barriers/chunk make write-after-read safe); weights double-buffered
// [buf][k:9][o:8][f:64] (compute reads at consecutive f -> conflict-free).
// 512 thr = (bq:8)x(f:64); thread: 8 o x 4 b (acc[8][4]); grid 256 -> 8
// waves/CU. In-flight/block/chunk ~86KB -> MLP ample. LDS 63KB. No min-waves
// launch_bounds (",N" VGPR-cap trap, r5/r7).
template <typename YT>
__global__ __launch_bounds__(512) void svconv_kernel(
    const float* __restrict__ x, const float* __restrict__ wgt,
    const float* __restrict__ bias, YT* __restrict__ y,
    float* __restrict__ psum, float* __restrict__ psumsq)
{
    __shared__ __align__(16) unsigned ldsX[3 * 32 * 68];     // [kh][b][w'] 26.1KB
    __shared__ __align__(16) unsigned ldsW[2 * 9 * 8 * 64];  // [buf][k][o][f] 36.9KB

    const int tid = threadIdx.x;
    const int f   = tid & 63;
    const int bq  = tid >> 6;                 // 0..7
    const int oq  = blockIdx.x >> 6;          // 0..3
    const int h   = blockIdx.x & 63;
    const int col = h * 64 + f;

    // ---- weight slots: tid<288 = (o:8)x(k:9)x(q:4); 16 floats x 2 p-rows ----
    const bool wOK = (tid < 288);
    int wg = 0, wl = 0;
    {
        int s = wOK ? tid : 0;
        int o_ = s / 36, rm = s - 36 * o_;
        int k_ = rm >> 2, q_ = rm & 3;
        wg = ((oq * 8 + o_) * 72 + k_) * F2 + h * 64 + 16 * q_;  // +cp*18*F2, pair +9*F2
        wl = (k_ * 8 + o_) * 64 + 16 * q_;
    }

    // ---- x slots: tid<384 = (kh:3)x(b:32)x(q:4); 16 floats x 2 channels ----
    bool xOK = false;
    int xg = 0, xl = 0;
    {
        int s = (tid < 384) ? tid : 0;
        int kh_ = s >> 7, b_ = (s >> 2) & 31, q_ = s & 3;
        int gh = h - 1 + kh_;
        xOK = (tid < 384) && ((unsigned)gh < 64u);
        xg = b_ * 32768 + gh * 64 + 16 * q_;          // + c*4096 at issue
        xl = (kh_ * 32 + b_) * 68 + 16 * q_;
    }

    // x tap indices (halo cols at w'=64 (left) and 65 (right), zero forever)
    const int wi0 = (f == 0)  ? 64 : f - 1;
    const int wi2 = (f == 63) ? 65 : f + 1;

    float bz[8];
#pragma unroll
    for (int j = 0; j < 8; ++j) bz[j] = bias[(oq * 8 + j) * F2 + col];

    float acc[8][4];
#pragma unroll
    for (int j = 0; j < 8; ++j)
#pragma unroll
        for (int i = 0; i < 4; ++i) acc[j][i] = 0.f;

    float4 xr0[4], xr1[4], wr0[4], wr1[4];    // staged regs (one chunk in flight)

    auto ISSUEX = [&](int cp) {
        if (xOK) {
            const int c0 = xg + cp * 8192;
#pragma unroll
            for (int e = 0; e < 4; ++e) {
                xr0[e] = *(const float4*)(x + c0 + 4 * e);
                xr1[e] = *(const float4*)(x + c0 + 4096 + 4 * e);
            }
        }
    };
    auto ISSUEW = [&](int cp) {
        if (wOK) {
            const int g0 = wg + cp * 18 * F2;
#pragma unroll
            for (int e = 0; e < 4; ++e) {
                wr0[e] = *(const float4*)(wgt + g0 + 4 * e);
                wr1[e] = *(const float4*)(wgt + g0 + 9 * F2 + 4 * e);
            }
        }
    };
    auto WRITEX = [&]() {
        if (xOK) {
#pragma unroll
            for (int e = 0; e < 4; ++e) {
                uint4 pk;
                pk.x = pkh2f(xr0[e].x, xr1[e].x);
                pk.y = pkh2f(xr0[e].y, xr1[e].y);
                pk.z = pkh2f(xr0[e].z, xr1[e].z);
                pk.w = pkh2f(xr0[e].w, xr1[e].w);
                *(uint4*)&ldsX[xl + 4 * e] = pk;
            }
        }
    };
    auto WRITEW = [&](int buf) {
        if (wOK) {
#pragma unroll
            for (int e = 0; e < 4; ++e) {
                uint4 pk;
                pk.x = pkh2f(wr0[e].x, wr1[e].x);
                pk.y = pkh2f(wr0[e].y, wr1[e].y);
                pk.z = pkh2f(wr0[e].z, wr1[e].z);
                pk.w = pkh2f(wr0[e].w, wr1[e].w);
                *(uint4*)&ldsW[buf * 4608 + wl + 4 * e] = pk;
            }
        }
    };
    auto COMPUTE = [&](int wbuf) {
        const unsigned* wb = &ldsW[wbuf * 4608];
#pragma unroll
        for (int k = 0; k < 9; ++k) {
            const int kh = k / 3, kw = k - 3 * kh;
            const int wi = (kw == 0) ? wi0 : ((kw == 1) ? f : wi2);
            h2 wv[8];
#pragma unroll
            for (int j = 0; j < 8; ++j) wv[j] = bch2(wb[k * 512 + j * 64 + f]);
#pragma unroll
            for (int i = 0; i < 4; ++i) {
                h2 xv = bch2(ldsX[(kh * 32 + bq * 4 + i) * 68 + wi]);
#pragma unroll
                for (int j = 0; j < 8; ++j)
                    acc[j][i] = DOT2(wv[j], xv, acc[j][i]);
            }
        }
    };

    // ---- prologue: zero x LDS (halos stay zero forever); chunk0 staged ----
    ISSUEX(0); ISSUEW(0);
    for (int i = tid; i < 3 * 32 * 68; i += 512) ldsX[i] = 0u;
    __syncthreads();
    WRITEX(); WRITEW(0);
    ISSUEX(1); ISSUEW(1);
    __syncthreads();

#pragma unroll
    for (int cp = 0; cp < 4; ++cp) {
        COMPUTE(cp & 1);
        if (cp < 3) {
            __syncthreads();               // x reads done
            WRITEX(); WRITEW((cp + 1) & 1);
            if (cp < 2) { ISSUEX(cp + 2); ISSUEW(cp + 2); }
            __syncthreads();               // x writes done
        }
    }
    __syncthreads();                       // free ldsX for scratch reuse

    // ---- epilogue: bias, y store, BN partials ----
    float s_[8], ss_[8];
#pragma unroll
    for (int j = 0; j < 8; ++j) {
        s_[j] = 0.f; ss_[j] = 0.f;
#pragma unroll
        for (int i = 0; i < 4; ++i) {
            float a = acc[j][i] + bz[j];
            y[(size_t)((bq * 4 + i) * Oo + oq * 8 + j) * F2 + col] = (YT)a;
            s_[j] += a; ss_[j] = fmaf(a, a, ss_[j]);
        }
    }
    if (psum != nullptr) {
#pragma unroll
        for (int j = 0; j < 8; ++j)
#pragma unroll
            for (int d = 32; d >= 1; d >>= 1) {
                s_[j]  += __shfl_down(s_[j],  d, 64);
                ss_[j] += __shfl_down(ss_[j], d, 64);
            }
        float* scr = (float*)ldsX;          // [2][bq:8][o:8]
        if (f == 0) {
#pragma unroll
            for (int j = 0; j < 8; ++j) {
                scr[bq * 8 + j]      = s_[j];
                scr[64 + bq * 8 + j] = ss_[j];
            }
        }
        __syncthreads();
        if (tid < 64) {
            int j = tid >> 3, g = tid & 7;  // g = bq
            float v  = scr[g * 8 + j];
            float vv = scr[64 + g * 8 + j];
#pragma unroll
            for (int d = 4; d >= 1; d >>= 1) {
                v  += __shfl_down(v,  d, 8);
                vv += __shfl_down(vv, d, 8);
            }
            if (g == 0) {
                psum[(oq * 8 + j) * SLOTS + h]   = v;
                psumsq[(oq * 8 + j) * SLOTS + h] = vv;
            }
        }
    }
}

__global__ __launch_bounds__(64) void bnstats_kernel(
    const float* __restrict__ psum, const float* __restrict__ psumsq,
    const float* __restrict__ gamma, const float* __restrict__ beta,
    float* __restrict__ scsh)
{
    const int o = blockIdx.x;
    const int t = threadIdx.x;
    float s  = psum[o * SLOTS + t];
    float ss = psumsq[o * SLOTS + t];
#pragma unroll
    for (int d = 32; d >= 1; d >>= 1) {
        s  += __shfl_down(s, d, 64);
        ss += __shfl_down(ss, d, 64);
    }
    if (t == 0) {
        float mean = s / (float)NTOT;
        float var  = ss / (float)NTOT - mean * mean;
        float rstd = rsqrtf(var + 1e-5f);
        float scl  = gamma[o] * rstd;
        scsh[o]      = scl;
        scsh[Oo + o] = beta[o] - mean * scl;
    }
}

// ---- primary apply: read f16 y from ws, write fp32 to d_out ----
__global__ __launch_bounds__(256) void bnapply_f16_kernel(
    const _Float16* __restrict__ yh, const float* __restrict__ scsh,
    float* __restrict__ y)
{
    int i = blockIdx.x * 256 + threadIdx.x;    // 8-element packs; 524288 total
    h8 v = ((const h8*)yh)[i];
    int o = (i >> 9) & 31;
    float scl = scsh[o], sh = scsh[Oo + o];
    float4 lo, hi;
    lo.x = fmaf((float)v[0], scl, sh);
    lo.y = fmaf((float)v[1], scl, sh);
    lo.z = fmaf((float)v[2], scl, sh);
    lo.w = fmaf((float)v[3], scl, sh);
    hi.x = fmaf((float)v[4], scl, sh);
    hi.y = fmaf((float)v[5], scl, sh);
    hi.z = fmaf((float)v[6], scl, sh);
    hi.w = fmaf((float)v[7], scl, sh);
    ((float4*)y)[2 * i]     = lo;
    ((float4*)y)[2 * i + 1] = hi;
}

// ---- fallback apply: fp32 in place ----
__global__ __launch_bounds__(256) void bnapply_kernel(
    float* __restrict__ y, const float* __restrict__ scsh)
{
    int i = blockIdx.x * 256 + threadIdx.x;    // float4 index
    float4 v = ((const float4*)y)[i];
    int o = (i >> 10) & 31;
    float scl = scsh[o], sh = scsh[Oo + o];
    v.x = fmaf(v.x, scl, sh);
    v.y = fmaf(v.y, scl, sh);
    v.z = fmaf(v.z, scl, sh);
    v.w = fmaf(v.w, scl, sh);
    ((float4*)y)[i] = v;
}

// ---- tiny-scratch stats fallback: reduce y directly ----
__global__ __launch_bounds__(256) void bnreduce_y_kernel(
    const float* __restrict__ y, float* __restrict__ seg, float* __restrict__ segsq)
{
    const int o  = blockIdx.x >> 3;
    const int sg = blockIdx.x & 7;
    const int t  = threadIdx.x;
    float s = 0.f, ss = 0.f;
    for (int i = t; i < 4 * 1024; i += 256) {
        int b   = sg * 4 + (i >> 10);
        int fof = (i & 1023) * 4;
        float4 v = *(const float4*)(y + (size_t)(b * Oo + o) * F2 + fof);
        s  += (v.x + v.y) + (v.z + v.w);
        ss += v.x * v.x + v.y * v.y + v.z * v.z + v.w * v.w;
    }
#pragma unroll
    for (int d = 32; d >= 1; d >>= 1) {
        s  += __shfl_down(s, d, 64);
        ss += __shfl_down(ss, d, 64);
    }
    __shared__ float ls[4], lss[4];
    int wv = t >> 6, ln = t & 63;
    if (ln == 0) { ls[wv] = s; lss[wv] = ss; }
    __syncthreads();
    if (t == 0) {
        seg[blockIdx.x]   = (ls[0] + ls[1]) + (ls[2] + ls[3]);
        segsq[blockIdx.x] = (lss[0] + lss[1]) + (lss[2] + lss[3]);
    }
}

__global__ __launch_bounds__(256) void bnstats2_kernel(
    const float* __restrict__ seg, const float* __restrict__ segsq,
    const float* __restrict__ gamma, const float* __restrict__ beta,
    float* __restrict__ scsh)
{
    const int t = threadIdx.x;
    const int o = t >> 3, g = t & 7;
    float v  = seg[t];
    float vv = segsq[t];
#pragma unroll
    for (int d = 4; d >= 1; d >>= 1) {
        v  += __shfl_down(v,  d, 8);
        vv += __shfl_down(vv, d, 8);
    }
    if (g == 0) {
        float mean = v / (float)NTOT;
        float var  = vv / (float)NTOT - mean * mean;
        float rstd = rsqrtf(var + 1e-5f);
        float scl  = gamma[o] * rstd;
        scsh[o]      = scl;
        scsh[Oo + o] = beta[o] - mean * scl;
    }
}

extern "C" void kernel_launch(void* const* d_in, const int* in_sizes, int n_in,
                              void* d_out, int out_size, void* d_ws, size_t ws_size,
                              hipStream_t stream)
{
    const float* x     = (const float*)d_in[0];
    const float* wgt   = (const float*)d_in[1];
    const float* bias  = (const float*)d_in[2];
    const float* gamma = (const float*)d_in[3];
    const float* beta  = (const float*)d_in[4];
    float* y = (float*)d_out;

    const size_t n_elems    = (size_t)NTOT * Oo;              // 4,194,304
    const size_t yh_bytes   = n_elems * sizeof(_Float16);     // 8 MiB
    const size_t psum_bytes = (size_t)(2 * Oo * SLOTS + 2 * Oo) * sizeof(float);

    if (ws_size >= yh_bytes + psum_bytes) {
        // primary: f16 intermediate y in ws
        _Float16* yh  = (_Float16*)d_ws;
        float* psum   = (float*)((char*)d_ws + yh_bytes);     // [Oo][SLOTS]
        float* psumsq = psum + Oo * SLOTS;
        float* scsh   = psumsq + Oo * SLOTS;                  // [2][Oo]
        svconv_kernel<_Float16><<<GRID, 512, 0, stream>>>(x, wgt, bias, yh, psum, psumsq);
        bnstats_kernel<<<Oo, 64, 0, stream>>>(psum, psumsq, gamma, beta, scsh);
        bnapply_f16_kernel<<<(int)(n_elems / 8 / 256), 256, 0, stream>>>(yh, scsh, y);
    } else if (ws_size >= psum_bytes) {
        // secondary: fp32 y in d_out, partials in ws
        float* psum   = (float*)d_ws;
        float* psumsq = psum + Oo * SLOTS;
        float* scsh   = psumsq + Oo * SLOTS;
        svconv_kernel<float><<<GRID, 512, 0, stream>>>(x, wgt, bias, y, psum, psumsq);
        bnstats_kernel<<<Oo, 64, 0, stream>>>(psum, psumsq, gamma, beta, scsh);
        bnapply_kernel<<<(int)(n_elems / 4 / 256), 256, 0, stream>>>(y, scsh);
    } else {
        // tertiary: tiny scratch — reduce y directly
        float* seg   = (float*)d_ws;                          // [256]
        float* segsq = seg + 256;
        float* scsh  = segsq + 256;
        svconv_kernel<float><<<GRID, 512, 0, stream>>>(x, wgt, bias, y, nullptr, nullptr);
        bnreduce_y_kernel<<<256, 256, 0, stream>>>(y, seg, segsq);
        bnstats2_kernel<<<1, 256, 0, stream>>>(seg, segsq, gamma, beta, scsh);
        bnapply_kernel<<<(int)(n_elems / 4 / 256), 256, 0, stream>>>(y, scsh);
    }
}